// Round 23
// baseline (352.964 us; speedup 1.0000x reference)
//
#include <hip/hip_runtime.h>
#include <hip/hip_bf16.h>
#include <math.h>

#define B_   8
#define T_   12
#define NN   325
#define DD   256
#define HH   8
#define HD   32
#define FFD  1024
#define MTOK (B_*T_*NN)     // 31200 tokens
#define QKVD 768            // packed QKV row stride
#define ATT_SCALE 0.17677669529663687f   // 1/sqrt(32), folded into Q weights
#define LOG2E     1.4426950408889634f    // exp(x) = exp2(x*LOG2E); folded too
#define LN_EPS 1e-5f
#define MROWS 336           // padded key count (21 tiles of 16)

typedef __attribute__((ext_vector_type(8))) __bf16 bf16x8;
typedef __attribute__((ext_vector_type(4))) float  f32x4;
typedef __attribute__((ext_vector_type(4))) short  shortx4;
typedef __attribute__((ext_vector_type(8))) unsigned short ushortx8;

static __device__ inline float bf2f(unsigned short u) {
  union { float f; unsigned int i; } c; c.i = ((unsigned int)u) << 16; return c.f;
}

#if __has_builtin(__builtin_amdgcn_mfma_f32_16x16x16bf16_1k)
#define MFMA16(a,b,c) __builtin_amdgcn_mfma_f32_16x16x16bf16_1k((a),(b),(c),0,0,0)
#else
static __device__ inline f32x4 mfma16_fn(shortx4 a, shortx4 b, f32x4 c) {
  f32x4 d;
  asm volatile("v_mfma_f32_16x16x16_bf16 %0, %1, %2, %3"
               : "=v"(d) : "v"(a), "v"(b), "v"(c));
  return d;
}
#define MFMA16(a,b,c) mfma16_fn((a),(b),(c))
#endif

// ---------------------------------------------------------------------------
// Strip GEMM v2 (R16/R22 champion, replay-validated): 2 strips/wave,
// K-chunk 128, BP=136, uniform barrier discipline per chunk.
// ---------------------------------------------------------------------------
__global__ __launch_bounds__(256) void gemm_strip2(
    const __hip_bfloat16* __restrict__ A,
    const __hip_bfloat16* __restrict__ Wt,
    const float* __restrict__ bias,
    __hip_bfloat16* __restrict__ Cb,
    int Mr, int Nr, int Kr, int gelu)
{
  constexpr int BP = 136;
  __shared__ __hip_bfloat16 Bs[128 * BP];  // 34.8 KB

  const int NS  = Nr >> 7;
  const int nwg = gridDim.x;
  const int orig = blockIdx.x;
  const int qq = nwg >> 3, rr = nwg & 7;
  const int xcd = orig & 7, off = orig >> 3;
  const int id = (xcd < rr ? xcd * (qq + 1) : rr * (qq + 1) + (xcd - rr) * qq) + off;
  const int n0 = (id % NS) * 128;
  const int mg = id / NS;

  const int tid = threadIdx.x;
  const int w = tid >> 6, lane = tid & 63;
  const int lr = lane & 15, lg = lane >> 4;
  const int KC = Kr >> 7;

  float bv[8];
  #pragma unroll
  for (int j = 0; j < 8; ++j) bv[j] = bias[n0 + j * 16 + lr];

  const int strip0 = mg * 128 + w * 32;
  int ar0 = strip0 + lr;      if (ar0 >= Mr) ar0 = Mr - 1;
  int ar1 = strip0 + 16 + lr; if (ar1 >= Mr) ar1 = Mr - 1;

  f32x4 acc0[8] = {}, acc1[8] = {};

  for (int kc = 0; kc < KC; ++kc) {
    if (kc) __syncthreads();
    for (int u = tid; u < 128 * 16; u += 256) {
      int row = u >> 4, c8 = (u & 15) * 8;
      *(bf16x8*)&Bs[row * BP + c8] =
          *(const bf16x8*)&Wt[(size_t)(n0 + row) * Kr + kc * 128 + c8];
    }
    __syncthreads();

    const __hip_bfloat16* a0p = A + (size_t)ar0 * Kr + kc * 128 + lg * 8;
    const __hip_bfloat16* a1p = A + (size_t)ar1 * Kr + kc * 128 + lg * 8;
    bf16x8 a0[4], a1[4];
    #pragma unroll
    for (int k = 0; k < 4; ++k) {
      a0[k] = *(const bf16x8*)(a0p + k * 32);
      a1[k] = *(const bf16x8*)(a1p + k * 32);
    }
    #pragma unroll
    for (int k = 0; k < 4; ++k)
      #pragma unroll
      for (int j = 0; j < 8; ++j) {
        bf16x8 bfr = *(const bf16x8*)&Bs[(j * 16 + lr) * BP + k * 32 + lg * 8];
        acc0[j] = __builtin_amdgcn_mfma_f32_16x16x32_bf16(a0[k], bfr, acc0[j], 0, 0, 0);
        acc1[j] = __builtin_amdgcn_mfma_f32_16x16x32_bf16(a1[k], bfr, acc1[j], 0, 0, 0);
      }
  }

  #pragma unroll
  for (int j = 0; j < 8; ++j) {
    int col = n0 + j * 16 + lr;
    #pragma unroll
    for (int q = 0; q < 4; ++q) {
      int g0 = strip0 + lg * 4 + q;
      if (g0 < Mr) {
        float c = acc0[j][q] + bv[j];
        if (gelu) c = 0.5f * c * (1.f + erff(c * 0.70710678118654752f));
        Cb[(size_t)g0 * Nr + col] = __float2bfloat16(c);
      }
      int g1 = strip0 + 16 + lg * 4 + q;
      if (g1 < Mr) {
        float c = acc1[j][q] + bv[j];
        if (gelu) c = 0.5f * c * (1.f + erff(c * 0.70710678118654752f));
        Cb[(size_t)g1 * Nr + col] = __float2bfloat16(c);
      }
    }
  }
}

// ---------------------------------------------------------------------------
// Fused prep: weights transpose+cvt; Q weights/biases pre-scaled by
// ATT_SCALE*LOG2E (scores arrive in log2 domain -> exp2f saves a v_mul/exp).
// ---------------------------------------------------------------------------
struct PrepPtrs {
  const float* w[10];
  const float* b[6];
};

__global__ __launch_bounds__(256) void prep_all(
    PrepPtrs p, const int* __restrict__ adj, const float* __restrict__ x0,
    __hip_bfloat16* __restrict__ Wb, float* __restrict__ qkvb,
    float* __restrict__ maskf, __hip_bfloat16* __restrict__ x0b)
{
  __shared__ float t[32][33];
  const int z = blockIdx.z;

  if (z < 10) {
    const int Kz = (z == 9) ? 1024 : 256;
    const int Nz = (z == 8) ? 1024 : 256;
    if ((int)blockIdx.x >= Nz / 32 || (int)blockIdx.y >= Kz / 32) return;
    static const unsigned int dsto[10] = {0, 65536, 131072, 196608, 262144,
                                          327680, 393216, 458752, 524288, 786432};
    const float scale = (z == 0 || z == 3) ? ATT_SCALE * LOG2E : 1.f;
    const float* W = p.w[z];
    __hip_bfloat16* Wt = Wb + dsto[z];
    const int n0 = blockIdx.x * 32, k0 = blockIdx.y * 32;
    const int tx = threadIdx.x & 31, ty = threadIdx.x >> 5;
    #pragma unroll
    for (int i = 0; i < 32; i += 8)
      t[ty + i][tx] = W[(size_t)(k0 + ty + i) * Nz + n0 + tx];
    __syncthreads();
    #pragma unroll
    for (int i = 0; i < 32; i += 8)
      Wt[(size_t)(n0 + ty + i) * Kz + k0 + tx] = __float2bfloat16(t[tx][ty + i] * scale);
    return;
  }

  const int bx = blockIdx.x + blockIdx.y * 32;
  const int gid = bx * 256 + threadIdx.x;

  if (z == 10) {
    if (gid < 1536) {
      int i = gid & 767;
      int which = gid < 768 ? 0 : 1;
      int sub = i >> 8, j = i & 255;
      float v = p.b[which * 3 + sub][j];
      if (sub == 0) v *= ATT_SCALE * LOG2E;
      qkvb[which * 768 + i] = v;
    } else if (gid < 1536 + NN * MROWS) {
      int idx = gid - 1536;
      int l = idx / MROWS, m = idx % MROWS;
      float v;
      if (m >= NN) v = -INFINITY;
      else v = (adj[l * NN + m] != 0) ? 0.f : -1e30f;
      maskf[idx] = v;
    }
    return;
  }

  const int n4 = MTOK * DD / 4;
  for (int i = gid; i < n4; i += 262144) {
    float4 v = reinterpret_cast<const float4*>(x0)[i];
    union { shortx4 s; __hip_bfloat16 h[4]; } u;
    u.h[0] = __float2bfloat16(v.x); u.h[1] = __float2bfloat16(v.y);
    u.h[2] = __float2bfloat16(v.z); u.h[3] = __float2bfloat16(v.w);
    reinterpret_cast<shortx4*>(x0b)[i] = u.s;
  }
}

// ---------------------------------------------------------------------------
// MFMA spatial attention — champion structure; softmax in log2 domain
// (Q pre-scaled by ATT_SCALE*LOG2E, exp2f instead of __expf).
// Masked keys: s = st - 1e30 -> exp2(s-m)=0 exactly whenever any key is
// unmasked (identical behavior class to the validated __expf version).
// ---------------------------------------------------------------------------
__global__ __launch_bounds__(256) void spatial_attn_mfma(
    const __hip_bfloat16* __restrict__ qkv,
    const float* __restrict__ maskf,
    __hip_bfloat16* __restrict__ out)
{
  constexpr int KP = 40;
  constexpr int VP = 340;
  __shared__ unsigned short Kl[MROWS * KP];
  __shared__ unsigned short Vt[32 * VP];

  const int g = blockIdx.x, h = blockIdx.y;
  const int tid = threadIdx.x;
  const int w = tid >> 6, lane = tid & 63;
  const int lq = lane & 15, lg = lane >> 4;

  const size_t baseQ = (size_t)g * NN * QKVD + (size_t)h * HD;
  const size_t baseK = baseQ + 256;
  const size_t baseV = baseQ + 512;

  for (int idx = tid; idx < 32 * (VP - NN); idx += 256) {
    int d = idx / (VP - NN), kk = NN + idx % (VP - NN);
    Vt[d * VP + kk] = 0;
  }
  for (int idx = tid; idx < (MROWS - NN) * KP; idx += 256)
    Kl[NN * KP + idx] = 0;
  for (int idx = tid; idx < NN * 4; idx += 256) {
    int row = idx >> 2, cc = (idx & 3) * 8;
    union { bf16x8 v; unsigned short u[8]; } kv, vv;
    kv.v = *(const bf16x8*)&qkv[baseK + (size_t)row * QKVD + cc];
    *(bf16x8*)&Kl[row * KP + cc] = kv.v;
    vv.v = *(const bf16x8*)&qkv[baseV + (size_t)row * QKVD + cc];
    #pragma unroll
    for (int j = 0; j < 8; ++j) Vt[(cc + j) * VP + row] = vv.u[j];
  }
  __syncthreads();

  for (int qt = w; qt < 21; qt += 4) {
    const int query = qt * 16 + lq;
    const int qc = query < NN ? query : NN - 1;
    const bf16x8 qf = *(const bf16x8*)&qkv[baseQ + (size_t)qc * QKVD + lg * 8];
    const float* mrow = maskf + (size_t)qc * MROWS;

    f32x4 accL = {0.f, 0.f, 0.f, 0.f};
    f32x4 accH = {0.f, 0.f, 0.f, 0.f};
    float mrun = -INFINITY, lrun = 0.f;

    for (int t = 0; t < 21; ++t) {
      const int kbase = t * 16 + lg * 4;
      bf16x8 kf = *(const bf16x8*)&Kl[(t * 16 + lq) * KP + lg * 8];
      f32x4 st = __builtin_amdgcn_mfma_f32_16x16x32_bf16(
          kf, qf, (f32x4){0.f, 0.f, 0.f, 0.f}, 0, 0, 0);
      float4 mb = *(const float4*)&mrow[kbase];
      float s0 = st[0] + mb.x, s1 = st[1] + mb.y;
      float s2 = st[2] + mb.z, s3 = st[3] + mb.w;

      float tmax = fmaxf(fmaxf(s0, s1), fmaxf(s2, s3));
      tmax = fmaxf(tmax, __shfl_xor(tmax, 16));
      tmax = fmaxf(tmax, __shfl_xor(tmax, 32));
      const float mnew = fmaxf(mrun, tmax);
      const float corr = exp2f(mrun - mnew);   // exp2(-inf)=0 on first tile
      mrun = mnew;

      float p0 = exp2f(s0 - mnew), p1 = exp2f(s1 - mnew);
      float p2 = exp2f(s2 - mnew), p3 = exp2f(s3 - mnew);
      lrun = lrun * corr + ((p0 + p1) + (p2 + p3));   // per-lane partial
      accL *= corr; accH *= corr;

      union { shortx4 s4; __hip_bfloat16 hh[4]; } up;
      up.hh[0] = __float2bfloat16(p0); up.hh[1] = __float2bfloat16(p1);
      up.hh[2] = __float2bfloat16(p2); up.hh[3] = __float2bfloat16(p3);
      shortx4 vaL = *(const shortx4*)&Vt[lq * VP + kbase];
      shortx4 vaH = *(const shortx4*)&Vt[(lq + 16) * VP + kbase];
      accL = MFMA16(vaL, up.s4, accL);
      accH = MFMA16(vaH, up.s4, accH);
    }

    lrun += __shfl_xor(lrun, 16);
    lrun += __shfl_xor(lrun, 32);

    if (query < NN) {
      const float inv = 1.f / lrun;
      const size_t ob = ((size_t)(g * NN + query)) * DD + (size_t)h * HD;
      union { shortx4 s4; __hip_bfloat16 hh[4]; } uL, uH;
      #pragma unroll
      for (int q = 0; q < 4; ++q) {
        uL.hh[q] = __float2bfloat16(accL[q] * inv);
        uH.hh[q] = __float2bfloat16(accH[q] * inv);
      }
      *(shortx4*)&out[ob + lg * 4]      = uL.s4;
      *(shortx4*)&out[ob + 16 + lg * 4] = uH.s4;
    }
  }
}

// ---------------------------------------------------------------------------
// Temporal attention (causal, T=12), packed bf16 QKV. Q pre-scaled by
// ATT_SCALE*LOG2E -> exp2f softmax.
// ---------------------------------------------------------------------------
__global__ __launch_bounds__(256) void temporal_attn(
    const __hip_bfloat16* __restrict__ qkv, __hip_bfloat16* __restrict__ out)
{
  int idx = blockIdx.x * 256 + threadIdx.x;
  const int total = B_ * NN * HH * T_;
  if (idx >= total) return;

  int t  = idx % T_;
  int h  = (idx / T_) % HH;
  int n  = (idx / (T_ * HH)) % NN;
  int b  = idx / (T_ * HH * NN);

  const size_t tq = (size_t)((b * T_ + t) * NN + n) * QKVD + h * HD;
  float qr[HD];
  #pragma unroll
  for (int c8 = 0; c8 < 4; ++c8) {
    ushortx8 u = *(const ushortx8*)&qkv[tq + c8 * 8];
    #pragma unroll
    for (int j = 0; j < 8; ++j) qr[c8 * 8 + j] = bf2f(u[j]);
  }

  float o[HD] = {};
  float mrun = -INFINITY, lrun = 0.f;

  for (int tt = 0; tt <= t; ++tt) {
    const size_t tk = (size_t)((b * T_ + tt) * NN + n) * QKVD + h * HD;
    float s = 0.f;
    #pragma unroll
    for (int c8 = 0; c8 < 4; ++c8) {
      ushortx8 u = *(const ushortx8*)&qkv[tk + 256 + c8 * 8];
      #pragma unroll
      for (int j = 0; j < 8; ++j) s += qr[c8 * 8 + j] * bf2f(u[j]);
    }
    float mnew = fmaxf(mrun, s);
    float corr = exp2f(mrun - mnew);
    float p = exp2f(s - mnew);
    lrun = lrun * corr + p;
    #pragma unroll
    for (int c8 = 0; c8 < 4; ++c8) {
      ushortx8 u = *(const ushortx8*)&qkv[tk + 512 + c8 * 8];
      #pragma unroll
      for (int j = 0; j < 8; ++j) o[c8 * 8 + j] = o[c8 * 8 + j] * corr + p * bf2f(u[j]);
    }
    mrun = mnew;
  }

  float inv = 1.f / lrun;
  __hip_bfloat16* op = out + ((size_t)((b * T_ + t) * NN + n)) * DD + h * HD;
  #pragma unroll
  for (int d0 = 0; d0 < HD; d0 += 4) {
    union { shortx4 s; __hip_bfloat16 h4[4]; } u;
    #pragma unroll
    for (int j = 0; j < 4; ++j) u.h4[j] = __float2bfloat16(o[d0 + j] * inv);
    *reinterpret_cast<shortx4*>(op + d0) = u.s;
  }
}

// ---------------------------------------------------------------------------
__global__ __launch_bounds__(64) void add_ln(
    const float* __restrict__ x, const __hip_bfloat16* __restrict__ r,
    const float* __restrict__ w, const float* __restrict__ bb,
    float* __restrict__ y, __hip_bfloat16* __restrict__ ybf)
{
  const size_t row = blockIdx.x;
  const int lane = threadIdx.x;

  const float4 xv = reinterpret_cast<const float4*>(x + row * DD)[lane];
  union { shortx4 s4; unsigned short u[4]; } rv;
  rv.s4 = reinterpret_cast<const shortx4*>(r + row * DD)[lane];
  float e[4] = {xv.x + bf2f(rv.u[0]), xv.y + bf2f(rv.u[1]),
                xv.z + bf2f(rv.u[2]), xv.w + bf2f(rv.u[3])};

  float s  = e[0] + e[1] + e[2] + e[3];
  float ss = e[0]*e[0] + e[1]*e[1] + e[2]*e[2] + e[3]*e[3];
  #pragma unroll
  for (int off = 32; off > 0; off >>= 1) {
    s  += __shfl_xor(s,  off, 64);
    ss += __shfl_xor(ss, off, 64);
  }
  float mu  = s * (1.f / DD);
  float var = ss * (1.f / DD) - mu * mu;
  float rs  = rsqrtf(var + LN_EPS);

  const float4 wv = reinterpret_cast<const float4*>(w)[lane];
  const float4 bv = reinterpret_cast<const float4*>(bb)[lane];
  float o0 = (e[0] - mu) * rs * wv.x + bv.x;
  float o1 = (e[1] - mu) * rs * wv.y + bv.y;
  float o2 = (e[2] - mu) * rs * wv.z + bv.z;
  float o3 = (e[3] - mu) * rs * wv.w + bv.w;
  float4 yv = {o0, o1, o2, o3};
  reinterpret_cast<float4*>(y + row * DD)[lane] = yv;
  if (ybf) {
    union { shortx4 s4; __hip_bfloat16 h4[4]; } u;
    u.h4[0] = __float2bfloat16(o0); u.h4[1] = __float2bfloat16(o1);
    u.h4[2] = __float2bfloat16(o2); u.h4[3] = __float2bfloat16(o3);
    reinterpret_cast<shortx4*>(ybf + row * DD)[lane] = u.s4;
  }
}

// ---------------------------------------------------------------------------
extern "C" void kernel_launch(void* const* d_in, const int* in_sizes, int n_in,
                              void* d_out, int out_size, void* d_ws, size_t ws_size,
                              hipStream_t stream)
{
  const float* x0   = (const float*)d_in[0];
  const int*   adj  = (const int*)  d_in[1];
  const float* sa_wq = (const float*)d_in[2];
  const float* sa_bq = (const float*)d_in[3];
  const float* sa_wk = (const float*)d_in[4];
  const float* sa_bk = (const float*)d_in[5];
  const float* sa_wv = (const float*)d_in[6];
  const float* sa_bv = (const float*)d_in[7];
  const float* sa_wo = (const float*)d_in[8];
  const float* sa_bo = (const float*)d_in[9];
  const float* sa_lw = (const float*)d_in[10];
  const float* sa_lb = (const float*)d_in[11];
  const float* ta_wq = (const float*)d_in[12];
  const float* ta_bq = (const float*)d_in[13];
  const float* ta_wk = (const float*)d_in[14];
  const float* ta_bk = (const float*)d_in[15];
  const float* ta_wv = (const float*)d_in[16];
  const float* ta_bv = (const float*)d_in[17];
  const float* ta_wo = (const float*)d_in[18];
  const float* ta_bo = (const float*)d_in[19];
  const float* ta_lw = (const float*)d_in[20];
  const float* ta_lb = (const float*)d_in[21];
  const float* f_w1  = (const float*)d_in[22];
  const float* f_b1  = (const float*)d_in[23];
  const float* f_w2  = (const float*)d_in[24];
  const float* f_b2  = (const float*)d_in[25];
  const float* f_lw  = (const float*)d_in[26];
  const float* f_lb  = (const float*)d_in[27];

  float* out = (float*)d_out;
  float* ws  = (float*)d_ws;

  const size_t P = (size_t)MTOK * DD;           // 7,987,200 floats (32 MB)
  if (ws_size < 7 * P * sizeof(float)) return;

  float* R0 = ws;                                 // x2 fp32 [0,1P)
  __hip_bfloat16* QKVb = (__hip_bfloat16*)(ws + P);     // [M,768] bf16 [1P,2.5P)
  __hip_bfloat16* HIDb = (__hip_bfloat16*)(ws + P);     // [M,1024] bf16, stage C
  __hip_bfloat16* PRJ  = (__hip_bfloat16*)(ws + 3 * P); // proj out bf16
  float* R4 = ws + 4 * P;                         // x1 fp32
  __hip_bfloat16* X0b  = (__hip_bfloat16*)(ws + 5 * P);
  __hip_bfloat16* X1b  = (__hip_bfloat16*)(ws + 5 * P + P / 2);
  __hip_bfloat16* ATTb = (__hip_bfloat16*)(ws + 6 * P);
  __hip_bfloat16* Wb   = (__hip_bfloat16*)(ws + 6 * P + P / 2);

  __hip_bfloat16* sa_qkv_t = Wb;                 // [768][256]
  __hip_bfloat16* ta_qkv_t = Wb + 196608;
  __hip_bfloat16* sa_wo_t  = Wb + 393216;
  __hip_bfloat16* ta_wo_t  = Wb + 458752;
  __hip_bfloat16* f_w1_t   = Wb + 524288;        // [1024][256]
  __hip_bfloat16* f_w2_t   = Wb + 786432;        // [256][1024]
  float* qkvb  = (float*)(Wb + 1048576);         // sa[768] + ta[768]
  float* maskf = qkvb + 1536;                    // [NN][336] additive mask

  PrepPtrs pp;
  pp.w[0] = sa_wq; pp.w[1] = sa_wk; pp.w[2] = sa_wv;
  pp.w[3] = ta_wq; pp.w[4] = ta_wk; pp.w[5] = ta_wv;
  pp.w[6] = sa_wo; pp.w[7] = ta_wo; pp.w[8] = f_w1; pp.w[9] = f_w2;
  pp.b[0] = sa_bq; pp.b[1] = sa_bk; pp.b[2] = sa_bv;
  pp.b[3] = ta_bq; pp.b[4] = ta_bk; pp.b[5] = ta_bv;
  prep_all<<<dim3(32, 32, 12), 256, 0, stream>>>(pp, adj, x0, Wb, qkvb, maskf, X0b);

  const int MG = (MTOK + 127) / 128;   // 244
  auto gemmS = [&](const __hip_bfloat16* A, const __hip_bfloat16* Wt, const float* bias,
                   __hip_bfloat16* Cb, int Nr, int Kr, int gelu) {
    int nwg = (Nr / 128) * MG;
    gemm_strip2<<<nwg, 256, 0, stream>>>(A, Wt, bias, Cb, MTOK, Nr, Kr, gelu);
  };

  // ---- Stage A: spatial attention ----
  gemmS(X0b, sa_qkv_t, qkvb, QKVb, QKVD, DD, 0);
  spatial_attn_mfma<<<dim3(B_ * T_, HH), 256, 0, stream>>>(QKVb, maskf, ATTb);
  gemmS(ATTb, sa_wo_t, sa_bo, PRJ, DD, DD, 0);
  add_ln<<<MTOK, 64, 0, stream>>>(x0, PRJ, sa_lw, sa_lb, R4, X1b);   // x1: R4 + X1b

  // ---- Stage B: temporal attention ----
  gemmS(X1b, ta_qkv_t, qkvb + 768, QKVb, QKVD, DD, 0);
  {
    int total = B_ * NN * HH * T_;
    temporal_attn<<<(total + 255) / 256, 256, 0, stream>>>(QKVb, ATTb);
  }
  gemmS(ATTb, ta_wo_t, ta_bo, PRJ, DD, DD, 0);
  add_ln<<<MTOK, 64, 0, stream>>>(R4, PRJ, ta_lw, ta_lb, R0, X0b);   // x2: R0 + X0b

  // ---- Stage C: FFN ----
  gemmS(X0b, f_w1_t, f_b1, HIDb, FFD, DD, 1);                        // GELU, bf16 hidden
  gemmS(HIDb, f_w2_t, f_b2, PRJ, DD, FFD, 0);                        // K=1024
  add_ln<<<MTOK, 64, 0, stream>>>(R0, PRJ, f_lw, f_lb, out, nullptr);
}

// Round 24
// 344.450 us; speedup vs baseline: 1.0247x; 1.0247x over previous
//
#include <hip/hip_runtime.h>
#include <hip/hip_bf16.h>
#include <math.h>

#define B_   8
#define T_   12
#define NN   325
#define DD   256
#define HH   8
#define HD   32
#define FFD  1024
#define MTOK (B_*T_*NN)     // 31200 tokens
#define QKVD 768            // packed QKV row stride
#define ATT_SCALE 0.17677669529663687f   // 1/sqrt(32), folded into Q weights
#define LN_EPS 1e-5f
#define MROWS 336           // padded key count (21 tiles of 16)

typedef __attribute__((ext_vector_type(8))) __bf16 bf16x8;
typedef __attribute__((ext_vector_type(4))) float  f32x4;
typedef __attribute__((ext_vector_type(4))) short  shortx4;
typedef __attribute__((ext_vector_type(8))) unsigned short ushortx8;

static __device__ inline float bf2f(unsigned short u) {
  union { float f; unsigned int i; } c; c.i = ((unsigned int)u) << 16; return c.f;
}

#if __has_builtin(__builtin_amdgcn_mfma_f32_16x16x16bf16_1k)
#define MFMA16(a,b,c) __builtin_amdgcn_mfma_f32_16x16x16bf16_1k((a),(b),(c),0,0,0)
#else
static __device__ inline f32x4 mfma16_fn(shortx4 a, shortx4 b, f32x4 c) {
  f32x4 d;
  asm volatile("v_mfma_f32_16x16x16_bf16 %0, %1, %2, %3"
               : "=v"(d) : "v"(a), "v"(b), "v"(c));
  return d;
}
#define MFMA16(a,b,c) mfma16_fn((a),(b),(c))
#endif

// ---------------------------------------------------------------------------
// Strip GEMM v2 (R16/R22 champion, replay-validated twice at 345us):
// 2 strips/wave, K-chunk 128, BP=136, uniform barrier discipline per chunk,
// no inner barriers in the k-loop.
// ---------------------------------------------------------------------------
__global__ __launch_bounds__(256) void gemm_strip2(
    const __hip_bfloat16* __restrict__ A,
    const __hip_bfloat16* __restrict__ Wt,
    const float* __restrict__ bias,
    __hip_bfloat16* __restrict__ Cb,
    int Mr, int Nr, int Kr, int gelu)
{
  constexpr int BP = 136;
  __shared__ __hip_bfloat16 Bs[128 * BP];  // 34.8 KB

  const int NS  = Nr >> 7;
  const int nwg = gridDim.x;
  const int orig = blockIdx.x;
  const int qq = nwg >> 3, rr = nwg & 7;
  const int xcd = orig & 7, off = orig >> 3;
  const int id = (xcd < rr ? xcd * (qq + 1) : rr * (qq + 1) + (xcd - rr) * qq) + off;
  const int n0 = (id % NS) * 128;
  const int mg = id / NS;

  const int tid = threadIdx.x;
  const int w = tid >> 6, lane = tid & 63;
  const int lr = lane & 15, lg = lane >> 4;
  const int KC = Kr >> 7;

  float bv[8];
  #pragma unroll
  for (int j = 0; j < 8; ++j) bv[j] = bias[n0 + j * 16 + lr];

  const int strip0 = mg * 128 + w * 32;
  int ar0 = strip0 + lr;      if (ar0 >= Mr) ar0 = Mr - 1;
  int ar1 = strip0 + 16 + lr; if (ar1 >= Mr) ar1 = Mr - 1;

  f32x4 acc0[8] = {}, acc1[8] = {};

  for (int kc = 0; kc < KC; ++kc) {
    if (kc) __syncthreads();
    for (int u = tid; u < 128 * 16; u += 256) {
      int row = u >> 4, c8 = (u & 15) * 8;
      *(bf16x8*)&Bs[row * BP + c8] =
          *(const bf16x8*)&Wt[(size_t)(n0 + row) * Kr + kc * 128 + c8];
    }
    __syncthreads();

    const __hip_bfloat16* a0p = A + (size_t)ar0 * Kr + kc * 128 + lg * 8;
    const __hip_bfloat16* a1p = A + (size_t)ar1 * Kr + kc * 128 + lg * 8;
    bf16x8 a0[4], a1[4];
    #pragma unroll
    for (int k = 0; k < 4; ++k) {
      a0[k] = *(const bf16x8*)(a0p + k * 32);
      a1[k] = *(const bf16x8*)(a1p + k * 32);
    }
    #pragma unroll
    for (int k = 0; k < 4; ++k)
      #pragma unroll
      for (int j = 0; j < 8; ++j) {
        bf16x8 bfr = *(const bf16x8*)&Bs[(j * 16 + lr) * BP + k * 32 + lg * 8];
        acc0[j] = __builtin_amdgcn_mfma_f32_16x16x32_bf16(a0[k], bfr, acc0[j], 0, 0, 0);
        acc1[j] = __builtin_amdgcn_mfma_f32_16x16x32_bf16(a1[k], bfr, acc1[j], 0, 0, 0);
      }
  }

  #pragma unroll
  for (int j = 0; j < 8; ++j) {
    int col = n0 + j * 16 + lr;
    #pragma unroll
    for (int q = 0; q < 4; ++q) {
      int g0 = strip0 + lg * 4 + q;
      if (g0 < Mr) {
        float c = acc0[j][q] + bv[j];
        if (gelu) c = 0.5f * c * (1.f + erff(c * 0.70710678118654752f));
        Cb[(size_t)g0 * Nr + col] = __float2bfloat16(c);
      }
      int g1 = strip0 + 16 + lg * 4 + q;
      if (g1 < Mr) {
        float c = acc1[j][q] + bv[j];
        if (gelu) c = 0.5f * c * (1.f + erff(c * 0.70710678118654752f));
        Cb[(size_t)g1 * Nr + col] = __float2bfloat16(c);
      }
    }
  }
}

// ---------------------------------------------------------------------------
// Fused prep: weights transpose+cvt (Q pre-scaled), biases, mask table, x0 cvt.
// ---------------------------------------------------------------------------
struct PrepPtrs {
  const float* w[10];
  const float* b[6];
};

__global__ __launch_bounds__(256) void prep_all(
    PrepPtrs p, const int* __restrict__ adj, const float* __restrict__ x0,
    __hip_bfloat16* __restrict__ Wb, float* __restrict__ qkvb,
    float* __restrict__ maskf, __hip_bfloat16* __restrict__ x0b)
{
  __shared__ float t[32][33];
  const int z = blockIdx.z;

  if (z < 10) {
    const int Kz = (z == 9) ? 1024 : 256;
    const int Nz = (z == 8) ? 1024 : 256;
    if ((int)blockIdx.x >= Nz / 32 || (int)blockIdx.y >= Kz / 32) return;
    static const unsigned int dsto[10] = {0, 65536, 131072, 196608, 262144,
                                          327680, 393216, 458752, 524288, 786432};
    const float scale = (z == 0 || z == 3) ? ATT_SCALE : 1.f;
    const float* W = p.w[z];
    __hip_bfloat16* Wt = Wb + dsto[z];
    const int n0 = blockIdx.x * 32, k0 = blockIdx.y * 32;
    const int tx = threadIdx.x & 31, ty = threadIdx.x >> 5;
    #pragma unroll
    for (int i = 0; i < 32; i += 8)
      t[ty + i][tx] = W[(size_t)(k0 + ty + i) * Nz + n0 + tx];
    __syncthreads();
    #pragma unroll
    for (int i = 0; i < 32; i += 8)
      Wt[(size_t)(n0 + ty + i) * Kz + k0 + tx] = __float2bfloat16(t[tx][ty + i] * scale);
    return;
  }

  const int bx = blockIdx.x + blockIdx.y * 32;
  const int gid = bx * 256 + threadIdx.x;

  if (z == 10) {
    if (gid < 1536) {
      int i = gid & 767;
      int which = gid < 768 ? 0 : 1;
      int sub = i >> 8, j = i & 255;
      float v = p.b[which * 3 + sub][j];
      if (sub == 0) v *= ATT_SCALE;
      qkvb[which * 768 + i] = v;
    } else if (gid < 1536 + NN * MROWS) {
      int idx = gid - 1536;
      int l = idx / MROWS, m = idx % MROWS;
      float v;
      if (m >= NN) v = -INFINITY;
      else v = (adj[l * NN + m] != 0) ? 0.f : -1e30f;
      maskf[idx] = v;
    }
    return;
  }

  const int n4 = MTOK * DD / 4;
  for (int i = gid; i < n4; i += 262144) {
    float4 v = reinterpret_cast<const float4*>(x0)[i];
    union { shortx4 s; __hip_bfloat16 h[4]; } u;
    u.h[0] = __float2bfloat16(v.x); u.h[1] = __float2bfloat16(v.y);
    u.h[2] = __float2bfloat16(v.z); u.h[3] = __float2bfloat16(v.w);
    reinterpret_cast<shortx4*>(x0b)[i] = u.s;
  }
}

// ---------------------------------------------------------------------------
// MFMA spatial attention — R16/R22 champion (single-pass online softmax,
// additive mask, folded scale, deferred row-sum, phantom rows zeroed).
// ---------------------------------------------------------------------------
__global__ __launch_bounds__(256) void spatial_attn_mfma(
    const __hip_bfloat16* __restrict__ qkv,
    const float* __restrict__ maskf,
    __hip_bfloat16* __restrict__ out)
{
  constexpr int KP = 40;
  constexpr int VP = 340;
  __shared__ unsigned short Kl[MROWS * KP];
  __shared__ unsigned short Vt[32 * VP];

  const int g = blockIdx.x, h = blockIdx.y;
  const int tid = threadIdx.x;
  const int w = tid >> 6, lane = tid & 63;
  const int lq = lane & 15, lg = lane >> 4;

  const size_t baseQ = (size_t)g * NN * QKVD + (size_t)h * HD;
  const size_t baseK = baseQ + 256;
  const size_t baseV = baseQ + 512;

  for (int idx = tid; idx < 32 * (VP - NN); idx += 256) {
    int d = idx / (VP - NN), kk = NN + idx % (VP - NN);
    Vt[d * VP + kk] = 0;
  }
  for (int idx = tid; idx < (MROWS - NN) * KP; idx += 256)
    Kl[NN * KP + idx] = 0;
  for (int idx = tid; idx < NN * 4; idx += 256) {
    int row = idx >> 2, cc = (idx & 3) * 8;
    union { bf16x8 v; unsigned short u[8]; } kv, vv;
    kv.v = *(const bf16x8*)&qkv[baseK + (size_t)row * QKVD + cc];
    *(bf16x8*)&Kl[row * KP + cc] = kv.v;
    vv.v = *(const bf16x8*)&qkv[baseV + (size_t)row * QKVD + cc];
    #pragma unroll
    for (int j = 0; j < 8; ++j) Vt[(cc + j) * VP + row] = vv.u[j];
  }
  __syncthreads();

  for (int qt = w; qt < 21; qt += 4) {
    const int query = qt * 16 + lq;
    const int qc = query < NN ? query : NN - 1;
    const bf16x8 qf = *(const bf16x8*)&qkv[baseQ + (size_t)qc * QKVD + lg * 8];
    const float* mrow = maskf + (size_t)qc * MROWS;

    f32x4 accL = {0.f, 0.f, 0.f, 0.f};
    f32x4 accH = {0.f, 0.f, 0.f, 0.f};
    float mrun = -INFINITY, lrun = 0.f;

    for (int t = 0; t < 21; ++t) {
      const int kbase = t * 16 + lg * 4;
      bf16x8 kf = *(const bf16x8*)&Kl[(t * 16 + lq) * KP + lg * 8];
      f32x4 st = __builtin_amdgcn_mfma_f32_16x16x32_bf16(
          kf, qf, (f32x4){0.f, 0.f, 0.f, 0.f}, 0, 0, 0);
      float4 mb = *(const float4*)&mrow[kbase];
      float s0 = st[0] + mb.x, s1 = st[1] + mb.y;
      float s2 = st[2] + mb.z, s3 = st[3] + mb.w;

      float tmax = fmaxf(fmaxf(s0, s1), fmaxf(s2, s3));
      tmax = fmaxf(tmax, __shfl_xor(tmax, 16));
      tmax = fmaxf(tmax, __shfl_xor(tmax, 32));
      const float mnew = fmaxf(mrun, tmax);
      const float corr = __expf(mrun - mnew);   // exp(-inf)=0 on first tile
      mrun = mnew;

      float p0 = __expf(s0 - mnew), p1 = __expf(s1 - mnew);
      float p2 = __expf(s2 - mnew), p3 = __expf(s3 - mnew);
      lrun = lrun * corr + ((p0 + p1) + (p2 + p3));   // per-lane partial
      accL *= corr; accH *= corr;

      union { shortx4 s4; __hip_bfloat16 hh[4]; } up;
      up.hh[0] = __float2bfloat16(p0); up.hh[1] = __float2bfloat16(p1);
      up.hh[2] = __float2bfloat16(p2); up.hh[3] = __float2bfloat16(p3);
      shortx4 vaL = *(const shortx4*)&Vt[lq * VP + kbase];
      shortx4 vaH = *(const shortx4*)&Vt[(lq + 16) * VP + kbase];
      accL = MFMA16(vaL, up.s4, accL);
      accH = MFMA16(vaH, up.s4, accH);
    }

    lrun += __shfl_xor(lrun, 16);
    lrun += __shfl_xor(lrun, 32);

    if (query < NN) {
      const float inv = 1.f / lrun;
      const size_t ob = ((size_t)(g * NN + query)) * DD + (size_t)h * HD;
      union { shortx4 s4; __hip_bfloat16 hh[4]; } uL, uH;
      #pragma unroll
      for (int q = 0; q < 4; ++q) {
        uL.hh[q] = __float2bfloat16(accL[q] * inv);
        uH.hh[q] = __float2bfloat16(accH[q] * inv);
      }
      *(shortx4*)&out[ob + lg * 4]      = uL.s4;
      *(shortx4*)&out[ob + 16 + lg * 4] = uH.s4;
    }
  }
}

// ---------------------------------------------------------------------------
// Temporal attention (causal, T=12), packed bf16 QKV. Q pre-scaled.
// ---------------------------------------------------------------------------
__global__ __launch_bounds__(256) void temporal_attn(
    const __hip_bfloat16* __restrict__ qkv, __hip_bfloat16* __restrict__ out)
{
  int idx = blockIdx.x * 256 + threadIdx.x;
  const int total = B_ * NN * HH * T_;
  if (idx >= total) return;

  int t  = idx % T_;
  int h  = (idx / T_) % HH;
  int n  = (idx / (T_ * HH)) % NN;
  int b  = idx / (T_ * HH * NN);

  const size_t tq = (size_t)((b * T_ + t) * NN + n) * QKVD + h * HD;
  float qr[HD];
  #pragma unroll
  for (int c8 = 0; c8 < 4; ++c8) {
    ushortx8 u = *(const ushortx8*)&qkv[tq + c8 * 8];
    #pragma unroll
    for (int j = 0; j < 8; ++j) qr[c8 * 8 + j] = bf2f(u[j]);
  }

  float o[HD] = {};
  float mrun = -INFINITY, lrun = 0.f;

  for (int tt = 0; tt <= t; ++tt) {
    const size_t tk = (size_t)((b * T_ + tt) * NN + n) * QKVD + h * HD;
    float s = 0.f;
    #pragma unroll
    for (int c8 = 0; c8 < 4; ++c8) {
      ushortx8 u = *(const ushortx8*)&qkv[tk + 256 + c8 * 8];
      #pragma unroll
      for (int j = 0; j < 8; ++j) s += qr[c8 * 8 + j] * bf2f(u[j]);
    }
    float mnew = fmaxf(mrun, s);
    float corr = __expf(mrun - mnew);
    float p = __expf(s - mnew);
    lrun = lrun * corr + p;
    #pragma unroll
    for (int c8 = 0; c8 < 4; ++c8) {
      ushortx8 u = *(const ushortx8*)&qkv[tk + 512 + c8 * 8];
      #pragma unroll
      for (int j = 0; j < 8; ++j) o[c8 * 8 + j] = o[c8 * 8 + j] * corr + p * bf2f(u[j]);
    }
    mrun = mnew;
  }

  float inv = 1.f / lrun;
  __hip_bfloat16* op = out + ((size_t)((b * T_ + t) * NN + n)) * DD + h * HD;
  #pragma unroll
  for (int d0 = 0; d0 < HD; d0 += 4) {
    union { shortx4 s; __hip_bfloat16 h4[4]; } u;
    #pragma unroll
    for (int j = 0; j < 4; ++j) u.h4[j] = __float2bfloat16(o[d0 + j] * inv);
    *reinterpret_cast<shortx4*>(op + d0) = u.s;
  }
}

// ---------------------------------------------------------------------------
__global__ __launch_bounds__(64) void add_ln(
    const float* __restrict__ x, const __hip_bfloat16* __restrict__ r,
    const float* __restrict__ w, const float* __restrict__ bb,
    float* __restrict__ y, __hip_bfloat16* __restrict__ ybf)
{
  const size_t row = blockIdx.x;
  const int lane = threadIdx.x;

  const float4 xv = reinterpret_cast<const float4*>(x + row * DD)[lane];
  union { shortx4 s4; unsigned short u[4]; } rv;
  rv.s4 = reinterpret_cast<const shortx4*>(r + row * DD)[lane];
  float e[4] = {xv.x + bf2f(rv.u[0]), xv.y + bf2f(rv.u[1]),
                xv.z + bf2f(rv.u[2]), xv.w + bf2f(rv.u[3])};

  float s  = e[0] + e[1] + e[2] + e[3];
  float ss = e[0]*e[0] + e[1]*e[1] + e[2]*e[2] + e[3]*e[3];
  #pragma unroll
  for (int off = 32; off > 0; off >>= 1) {
    s  += __shfl_xor(s,  off, 64);
    ss += __shfl_xor(ss, off, 64);
  }
  float mu  = s * (1.f / DD);
  float var = ss * (1.f / DD) - mu * mu;
  float rs  = rsqrtf(var + LN_EPS);

  const float4 wv = reinterpret_cast<const float4*>(w)[lane];
  const float4 bv = reinterpret_cast<const float4*>(bb)[lane];
  float o0 = (e[0] - mu) * rs * wv.x + bv.x;
  float o1 = (e[1] - mu) * rs * wv.y + bv.y;
  float o2 = (e[2] - mu) * rs * wv.z + bv.z;
  float o3 = (e[3] - mu) * rs * wv.w + bv.w;
  float4 yv = {o0, o1, o2, o3};
  reinterpret_cast<float4*>(y + row * DD)[lane] = yv;
  if (ybf) {
    union { shortx4 s4; __hip_bfloat16 h4[4]; } u;
    u.h4[0] = __float2bfloat16(o0); u.h4[1] = __float2bfloat16(o1);
    u.h4[2] = __float2bfloat16(o2); u.h4[3] = __float2bfloat16(o3);
    reinterpret_cast<shortx4*>(ybf + row * DD)[lane] = u.s4;
  }
}

// ---------------------------------------------------------------------------
extern "C" void kernel_launch(void* const* d_in, const int* in_sizes, int n_in,
                              void* d_out, int out_size, void* d_ws, size_t ws_size,
                              hipStream_t stream)
{
  const float* x0   = (const float*)d_in[0];
  const int*   adj  = (const int*)  d_in[1];
  const float* sa_wq = (const float*)d_in[2];
  const float* sa_bq = (const float*)d_in[3];
  const float* sa_wk = (const float*)d_in[4];
  const float* sa_bk = (const float*)d_in[5];
  const float* sa_wv = (const float*)d_in[6];
  const float* sa_bv = (const float*)d_in[7];
  const float* sa_wo = (const float*)d_in[8];
  const float* sa_bo = (const float*)d_in[9];
  const float* sa_lw = (const float*)d_in[10];
  const float* sa_lb = (const float*)d_in[11];
  const float* ta_wq = (const float*)d_in[12];
  const float* ta_bq = (const float*)d_in[13];
  const float* ta_wk = (const float*)d_in[14];
  const float* ta_bk = (const float*)d_in[15];
  const float* ta_wv = (const float*)d_in[16];
  const float* ta_bv = (const float*)d_in[17];
  const float* ta_wo = (const float*)d_in[18];
  const float* ta_bo = (const float*)d_in[19];
  const float* ta_lw = (const float*)d_in[20];
  const float* ta_lb = (const float*)d_in[21];
  const float* f_w1  = (const float*)d_in[22];
  const float* f_b1  = (const float*)d_in[23];
  const float* f_w2  = (const float*)d_in[24];
  const float* f_b2  = (const float*)d_in[25];
  const float* f_lw  = (const float*)d_in[26];
  const float* f_lb  = (const float*)d_in[27];

  float* out = (float*)d_out;
  float* ws  = (float*)d_ws;

  const size_t P = (size_t)MTOK * DD;           // 7,987,200 floats (32 MB)
  if (ws_size < 7 * P * sizeof(float)) return;

  float* R0 = ws;                                 // x2 fp32 [0,1P)
  __hip_bfloat16* QKVb = (__hip_bfloat16*)(ws + P);     // [M,768] bf16 [1P,2.5P)
  __hip_bfloat16* HIDb = (__hip_bfloat16*)(ws + P);     // [M,1024] bf16, stage C
  __hip_bfloat16* PRJ  = (__hip_bfloat16*)(ws + 3 * P); // proj out bf16
  float* R4 = ws + 4 * P;                         // x1 fp32
  __hip_bfloat16* X0b  = (__hip_bfloat16*)(ws + 5 * P);
  __hip_bfloat16* X1b  = (__hip_bfloat16*)(ws + 5 * P + P / 2);
  __hip_bfloat16* ATTb = (__hip_bfloat16*)(ws + 6 * P);
  __hip_bfloat16* Wb   = (__hip_bfloat16*)(ws + 6 * P + P / 2);

  __hip_bfloat16* sa_qkv_t = Wb;                 // [768][256]
  __hip_bfloat16* ta_qkv_t = Wb + 196608;
  __hip_bfloat16* sa_wo_t  = Wb + 393216;
  __hip_bfloat16* ta_wo_t  = Wb + 458752;
  __hip_bfloat16* f_w1_t   = Wb + 524288;        // [1024][256]
  __hip_bfloat16* f_w2_t   = Wb + 786432;        // [256][1024]
  float* qkvb  = (float*)(Wb + 1048576);         // sa[768] + ta[768]
  float* maskf = qkvb + 1536;                    // [NN][336] additive mask

  PrepPtrs pp;
  pp.w[0] = sa_wq; pp.w[1] = sa_wk; pp.w[2] = sa_wv;
  pp.w[3] = ta_wq; pp.w[4] = ta_wk; pp.w[5] = ta_wv;
  pp.w[6] = sa_wo; pp.w[7] = ta_wo; pp.w[8] = f_w1; pp.w[9] = f_w2;
  pp.b[0] = sa_bq; pp.b[1] = sa_bk; pp.b[2] = sa_bv;
  pp.b[3] = ta_bq; pp.b[4] = ta_bk; pp.b[5] = ta_bv;
  prep_all<<<dim3(32, 32, 12), 256, 0, stream>>>(pp, adj, x0, Wb, qkvb, maskf, X0b);

  const int MG = (MTOK + 127) / 128;   // 244
  auto gemmS = [&](const __hip_bfloat16* A, const __hip_bfloat16* Wt, const float* bias,
                   __hip_bfloat16* Cb, int Nr, int Kr, int gelu) {
    int nwg = (Nr / 128) * MG;
    gemm_strip2<<<nwg, 256, 0, stream>>>(A, Wt, bias, Cb, MTOK, Nr, Kr, gelu);
  };

  // ---- Stage A: spatial attention ----
  gemmS(X0b, sa_qkv_t, qkvb, QKVb, QKVD, DD, 0);
  spatial_attn_mfma<<<dim3(B_ * T_, HH), 256, 0, stream>>>(QKVb, maskf, ATTb);
  gemmS(ATTb, sa_wo_t, sa_bo, PRJ, DD, DD, 0);
  add_ln<<<MTOK, 64, 0, stream>>>(x0, PRJ, sa_lw, sa_lb, R4, X1b);   // x1: R4 + X1b

  // ---- Stage B: temporal attention ----
  gemmS(X1b, ta_qkv_t, qkvb + 768, QKVb, QKVD, DD, 0);
  {
    int total = B_ * NN * HH * T_;
    temporal_attn<<<(total + 255) / 256, 256, 0, stream>>>(QKVb, ATTb);
  }
  gemmS(ATTb, ta_wo_t, ta_bo, PRJ, DD, DD, 0);
  add_ln<<<MTOK, 64, 0, stream>>>(R4, PRJ, ta_lw, ta_lb, R0, X0b);   // x2: R0 + X0b

  // ---- Stage C: FFN ----
  gemmS(X0b, f_w1_t, f_b1, HIDb, FFD, DD, 1);                        // GELU, bf16 hidden
  gemmS(HIDb, f_w2_t, f_b2, PRJ, DD, FFD, 0);                        // K=1024
  add_ln<<<MTOK, 64, 0, stream>>>(R0, PRJ, f_lw, f_lb, out, nullptr);
}